// Round 12
// baseline (582.398 us; speedup 1.0000x reference)
//
#include <hip/hip_runtime.h>
#include <hip/hip_bf16.h>
#include <math.h>

#define H 511
#define L 2048
#define NST 32
#define NLAYERS 4
#define LN_EPS 1e-5f
#define NCH 32             // conv chunks per channel
#define TC (L / NCH)       // 64 steps per chunk
#define HN (H * NST)       // 16352
#define HP 512             // K padded
#define GBK 64
#define GBN 64
#define NSTRIPE 16         // LN h-stripes of 32
#define NBLK 256           // persistent grid: one block always fits a CU

typedef __attribute__((ext_vector_type(8))) short short8;
typedef __attribute__((ext_vector_type(4))) float f32x4;

__device__ __forceinline__ ushort f2bf(float v) {
    __hip_bfloat16 b = __float2bfloat16(v);
    return *reinterpret_cast<ushort*>(&b);
}

template <int CTRL, int ROW_MASK>
__device__ __forceinline__ float dpp_add(float x) {
    int r = __builtin_amdgcn_update_dpp(0, __float_as_int(x), CTRL, ROW_MASK, 0xf, true);
    return x + __int_as_float(r);
}
__device__ __forceinline__ float reduce32_to_lane31(float p) {
    p = dpp_add<0x111, 0xf>(p);  // row_shr:1
    p = dpp_add<0x112, 0xf>(p);  // row_shr:2
    p = dpp_add<0x114, 0xf>(p);  // row_shr:4
    p = dpp_add<0x118, 0xf>(p);  // row_shr:8
    p = dpp_add<0x142, 0xa>(p);  // row_bcast:15 into rows 1,3
    return p;                    // lane31 = sum(0..31), lane63 = sum(32..63)
}

__device__ __forceinline__ float gelu_tanh(float v) {
    const float c0 = 0.7978845608028654f;  // sqrt(2/pi)
    float t = tanhf(c0 * (v + 0.044715f * v * v * v));
    return 0.5f * v * (1.0f + t);
}

// Count+generation grid barrier. Safe: 256 blocks, each fits one CU
// (launch_bounds caps VGPR at 128, LDS 34.8K), so all blocks co-resident.
// Re-entrant: cnt returns to 0 after each barrier.
__device__ __forceinline__ void grid_barrier(unsigned* cnt, unsigned* gen) {
    __syncthreads();
    if (threadIdx.x == 0) {
        __threadfence();   // agent-scope: L2 writeback for cross-XCD visibility
        unsigned g0 = __hip_atomic_load(gen, __ATOMIC_RELAXED, __HIP_MEMORY_SCOPE_AGENT);
        unsigned arr = __hip_atomic_fetch_add(cnt, 1u, __ATOMIC_ACQ_REL, __HIP_MEMORY_SCOPE_AGENT);
        if (arr == NBLK - 1u) {
            __hip_atomic_store(cnt, 0u, __ATOMIC_RELAXED, __HIP_MEMORY_SCOPE_AGENT);
            __hip_atomic_fetch_add(gen, 1u, __ATOMIC_RELEASE, __HIP_MEMORY_SCOPE_AGENT);
        } else {
            while (__hip_atomic_load(gen, __ATOMIC_ACQUIRE, __HIP_MEMORY_SCOPE_AGENT) == g0)
                __builtin_amdgcn_s_sleep(2);
        }
    }
    __syncthreads();
}

// ---------------------------------------------------------------------------
// Persistent megakernel: pre + 4x(conv, glu) + final LN, one dispatch.
// ---------------------------------------------------------------------------
__global__ __launch_bounds__(1024, 4) void s4_mega(
    const float* __restrict__ Z,
    const float* __restrict__ log_dt,
    const float* __restrict__ A_real_log,
    const float* __restrict__ A_imag,
    const float* __restrict__ C_re,
    const float* __restrict__ C_im,
    const float* __restrict__ D_skip,
    const float* __restrict__ glu_w,
    const float* __restrict__ glu_b,
    const float* __restrict__ ln_g,
    const float* __restrict__ ln_b,
    float* __restrict__ out,
    float* __restrict__ wr_, float* __restrict__ wi_,
    float* __restrict__ cr_, float* __restrict__ ci_,
    float* __restrict__ psumA, float* __restrict__ psqA,
    float* __restrict__ psumB, float* __restrict__ psqB,
    ushort* __restrict__ yb, ushort* __restrict__ wbf,
    unsigned* __restrict__ gcnt, unsigned* __restrict__ ggen)
{
    __shared__ __align__(16) unsigned char smem[34816];
    const int tid = threadIdx.x;
    const int bid = blockIdx.x;

    // ---------------- pre: coefs + W->bf16 (grid-strided) ------------------
    #pragma unroll
    for (int ii = 0; ii < 2; ++ii) {
        int idx = (ii * NBLK + bid) * 1024 + tid;
        if (idx < HN) {
            int h = idx / NST;
            float Ar = -expf(A_real_log[idx]);
            float Ai = A_imag[idx];
            float dt = expf(log_dt[h]);
            float dr = Ar * dt, di = Ai * dt;
            float er = expf(dr);
            float wv = er * cosf(di);
            float wiv = er * sinf(di);
            float den = Ar * Ar + Ai * Ai;
            float a = wv - 1.0f, b = wiv;
            float inv = 1.0f / den;
            float qr = (a * Ar + b * Ai) * inv;
            float qi = (b * Ar - a * Ai) * inv;
            wr_[idx] = wv; wi_[idx] = wiv;
            cr_[idx] = 2.0f * (C_re[idx] * qr - C_im[idx] * qi);
            ci_[idx] = 2.0f * (C_re[idx] * qi + C_im[idx] * qr);
        }
        if (idx < 2 * H * HP) {
            int r = idx / HP, k = idx % HP;
            float v = (k < H) ? glu_w[(size_t)r * H + k] : 0.0f;
            wbf[idx] = f2bf(v);
        }
    }
    grid_barrier(gcnt, ggen);

    for (int layer = 0; layer < NLAYERS; ++layer) {
        const int donorm = (layer > 0);
        const float* zsrc = (layer == 0) ? Z : out;
        float* psum_c = (layer & 1) ? psumB : psumA;
        float* psq_c  = (layer & 1) ? psqB  : psqA;
        const float* psum_p = (layer & 1) ? psumA : psumB;
        const float* psq_p  = (layer & 1) ? psqA  : psqB;

        // ---------------- conv: channels bid and bid+NBLK ------------------
        {
            float* zs  = (float*)smem;                 // 8 KB
            float* ber = (float*)(smem + 8192);        // 4 KB
            float* bei = (float*)(smem + 12288);       // 4 KB
            float* ysf = (float*)(smem + 16384);       // 8 KB
            const int wv2  = tid >> 6;
            const int half = (tid >> 5) & 1;
            const int ln   = tid & 31;
            const int cch  = wv2 * 2 + half;           // chunk 0..31

            for (int rep = 0; rep < 2; ++rep) {
                const int ch = bid + rep * NBLK;
                const bool valid = (ch < H);
                const int h = valid ? ch : 0;

                // stage z row (2 cols/thread) with optional inline LN
                {
                    const int c0 = tid * 2;
                    float2 v = *(const float2*)&zsrc[(size_t)h * L + c0];
                    if (donorm) {
                        float2 S = {0.f, 0.f}, Q = {0.f, 0.f};
                        #pragma unroll
                        for (int k = 0; k < NSTRIPE; ++k) {
                            float2 sv = *(const float2*)&psum_p[(size_t)k * L + c0];
                            float2 qv = *(const float2*)&psq_p[(size_t)k * L + c0];
                            S.x += sv.x; S.y += sv.y;
                            Q.x += qv.x; Q.y += qv.y;
                        }
                        const float invH = 1.0f / (float)H;
                        float mu0 = S.x * invH, mu1 = S.y * invH;
                        float rs0 = rsqrtf(Q.x * invH - mu0 * mu0 + LN_EPS);
                        float rs1 = rsqrtf(Q.y * invH - mu1 * mu1 + LN_EPS);
                        float gh = ln_g[h], bh = ln_b[h];
                        v.x = (v.x - mu0) * rs0 * gh + bh;
                        v.y = (v.y - mu1) * rs1 * gh + bh;
                    }
                    *(float2*)&zs[tid * 2] = v;
                }
                const int cidx = h * NST + ln;
                const float wrv = wr_[cidx], wiv = wi_[cidx];
                const float crv = cr_[cidx], civ = ci_[cidx];
                const float Dh = D_skip[h];
                __syncthreads();

                // phase 1: local scan of chunk cch (carry 0)
                float sr = 0.f, si = 0.f;
                {
                    const float* zp = &zs[cch * TC];
                    #pragma unroll 4
                    for (int l = 0; l < TC; ++l) {
                        float zl = zp[l];
                        float nsr = fmaf(wrv, sr, fmaf(-wiv, si, zl));
                        float nsi = fmaf(wrv, si, wiv * sr);
                        sr = nsr; si = nsi;
                    }
                }
                ber[cch * NST + ln] = sr;
                bei[cch * NST + ln] = si;
                __syncthreads();

                // phase 2: threads 0..31 combine the 32 chunk states
                if (tid < 32) {
                    float wtr = wrv, wti = wiv;
                    #pragma unroll
                    for (int k = 0; k < 6; ++k) {      // w^64
                        float nr = wtr * wtr - wti * wti;
                        float ni = 2.0f * wtr * wti;
                        wtr = nr; wti = ni;
                    }
                    float er = 0.f, ei = 0.f;
                    #pragma unroll
                    for (int cc = 0; cc < NCH; ++cc) {
                        float s_r = ber[cc * NST + tid], s_i = bei[cc * NST + tid];
                        ber[cc * NST + tid] = er; bei[cc * NST + tid] = ei;
                        float ner = fmaf(wtr, er, fmaf(-wti, ei, s_r));
                        float nei = fmaf(wtr, ei, fmaf(wti, er, s_i));
                        er = ner; ei = nei;
                    }
                }
                __syncthreads();

                // phase 3: rescan with carry + C-dot + reduce + D-skip
                sr = ber[cch * NST + ln];
                si = bei[cch * NST + ln];
                {
                    const float* zp = &zs[cch * TC];
                    float* yp = &ysf[cch * TC];
                    for (int l = 0; l < TC; ++l) {
                        float zl = zp[l];
                        float nsr = fmaf(wrv, sr, fmaf(-wiv, si, zl));
                        float nsi = fmaf(wrv, si, wiv * sr);
                        sr = nsr; si = nsi;
                        float p = fmaf(crv, sr, -civ * si);
                        p = reduce32_to_lane31(p);
                        if (ln == 31) yp[l] = fmaf(Dh, zl, p);
                    }
                }
                __syncthreads();

                // epilogue: all lanes gelu + bf16 (guarded store)
                if (valid) {
                    ushort2 v;
                    v.x = f2bf(gelu_tanh(ysf[tid * 2]));
                    v.y = f2bf(gelu_tanh(ysf[tid * 2 + 1]));
                    *(ushort2*)&yb[(size_t)h * L + tid * 2] = v;
                }
                __syncthreads();   // LDS reuse across reps
            }
        }
        grid_barrier(gcnt, ggen);

        // ---------------- glu: 2 teams of 256 thr, tiles bid*2+{0,1} -------
        {
            const int team = tid >> 8;           // 0..3; 0,1 active
            const int t    = tid & 255;
            const int gt   = bid * 2 + (team & 1);   // tile 0..511
            const bool act = (team < 2);
            unsigned char* base = smem + (team & 1) * 17408;
            ushort* As1 = (ushort*)base;               // 4 KB
            ushort* As2 = (ushort*)(base + 4096);      // 4 KB
            ushort* Bs  = (ushort*)(base + 8192);      // 8 KB
            float*  sls = (float*)(base + 16384);      // 2x64
            float*  slq = (float*)(base + 16896);      // 2x64

            const int l0 = (gt & 31) * GBN;
            const int h0 = (gt >> 5) * 32;
            const int wid = t >> 6;
            const int lane = t & 63;
            const int wrow = (wid >> 1) * 16;
            const int wcol = (wid & 1) * 32;

            f32x4 acc1[2] = {{0.f,0.f,0.f,0.f},{0.f,0.f,0.f,0.f}};
            f32x4 acc2[2] = {{0.f,0.f,0.f,0.f},{0.f,0.f,0.f,0.f}};

            const int ar = t >> 3;
            const int ak = t & 7;
            const int hq1 = (h0 + ar < H) ? (h0 + ar) : (H - 1);
            const int hq2 = hq1 + H;
            const int aswz = ak ^ (ar & 7);

            // B scatter indices: sub-team tm (64 thr) owns a 32x32 quadrant
            const int tm    = t >> 6;
            const int t64   = t & 63;
            const int ksub  = (tm & 1) * 32;
            const int lsub  = (tm >> 1) * 32;
            const int bkl   = t64 >> 1;
            const int bhalf = t64 & 1;
            const int kloc  = ksub + bkl;           // k-local 0..63
            const int oct   = kloc >> 3;
            const int kin   = kloc & 7;

            for (int k0 = 0; k0 < HP; k0 += GBK) {
                if (act) {
                    short8 va1 = *(const short8*)&wbf[(size_t)hq1 * HP + k0 + ak * 8];
                    short8 va2 = *(const short8*)&wbf[(size_t)hq2 * HP + k0 + ak * 8];
                    *(short8*)&As1[ar * GBK + aswz * 8] = va1;
                    *(short8*)&As2[ar * GBK + aswz * 8] = va2;

                    const int kg = k0 + kloc;       // global k = y channel
                    short8 v0 = {0,0,0,0,0,0,0,0}, v1 = {0,0,0,0,0,0,0,0};
                    if (kg < H) {
                        const ushort* row = &yb[(size_t)kg * L + l0 + lsub + bhalf * 16];
                        v0 = *(const short8*)&row[0];
                        v1 = *(const short8*)&row[8];
                    }
                    #pragma unroll
                    for (int j = 0; j < 8; ++j) {
                        int Lr = lsub + bhalf * 16 + j;
                        Bs[Lr * GBK + ((oct ^ (Lr & 7)) << 3) + kin] = (ushort)v0[j];
                    }
                    #pragma unroll
                    for (int j = 0; j < 8; ++j) {
                        int Lr = lsub + bhalf * 16 + 8 + j;
                        Bs[Lr * GBK + ((oct ^ (Lr & 7)) << 3) + kin] = (ushort)v1[j];
                    }
                }
                __syncthreads();
                if (act) {
                    #pragma unroll
                    for (int kk = 0; kk < 2; ++kk) {
                        const int arow = wrow + (lane & 15);
                        const int kg = kk * 4 + (lane >> 4);
                        short8 a1 = *(const short8*)&As1[arow * GBK + (kg ^ (arow & 7)) * 8];
                        short8 a2 = *(const short8*)&As2[arow * GBK + (kg ^ (arow & 7)) * 8];
                        #pragma unroll
                        for (int nf = 0; nf < 2; ++nf) {
                            const int brow = wcol + nf * 16 + (lane & 15);
                            short8 b = *(const short8*)&Bs[brow * GBK + (kg ^ (brow & 7)) * 8];
                            acc1[nf] = __builtin_amdgcn_mfma_f32_16x16x32_bf16(a1, b, acc1[nf], 0, 0, 0);
                            acc2[nf] = __builtin_amdgcn_mfma_f32_16x16x32_bf16(a2, b, acc2[nf], 0, 0, 0);
                        }
                    }
                }
                __syncthreads();
            }

            // epilogue: GLU + (normalized) residual -> out, plus LN stats
            float ps[2] = {0.f, 0.f}, pq[2] = {0.f, 0.f};
            if (act) {
                #pragma unroll
                for (int nf = 0; nf < 2; ++nf) {
                    const int col = l0 + wcol + nf * 16 + (lane & 15);
                    float mu = 0.f, rs = 1.f;
                    if (donorm) {
                        float S = 0.f, Q = 0.f;
                        #pragma unroll
                        for (int k = 0; k < NSTRIPE; ++k) {
                            S += psum_p[(size_t)k * L + col];
                            Q += psq_p[(size_t)k * L + col];
                        }
                        const float invH = 1.0f / (float)H;
                        mu = S * invH;
                        rs = rsqrtf(Q * invH - mu * mu + LN_EPS);
                    }
                    #pragma unroll
                    for (int r = 0; r < 4; ++r) {
                        const int h = h0 + wrow + (lane >> 4) * 4 + r;
                        if (h < H) {
                            float zv = zsrc[(size_t)h * L + col];
                            if (donorm) zv = (zv - mu) * rs * ln_g[h] + ln_b[h];
                            float v1 = acc1[nf][r] + glu_b[h];
                            float v2 = acc2[nf][r] + glu_b[h + H];
                            float o = v1 * (1.0f / (1.0f + expf(-v2))) + zv;
                            out[(size_t)h * L + col] = o;
                            ps[nf] += o;
                            pq[nf] = fmaf(o, o, pq[nf]);
                        }
                    }
                }
                #pragma unroll
                for (int nf = 0; nf < 2; ++nf) {
                    ps[nf] += __shfl_xor(ps[nf], 16, 64);
                    ps[nf] += __shfl_xor(ps[nf], 32, 64);
                    pq[nf] += __shfl_xor(pq[nf], 16, 64);
                    pq[nf] += __shfl_xor(pq[nf], 32, 64);
                    if ((lane >> 4) == 0) {
                        int cl = wcol + nf * 16 + lane;
                        sls[(wid >> 1) * 64 + cl] = ps[nf];
                        slq[(wid >> 1) * 64 + cl] = pq[nf];
                    }
                }
            }
            __syncthreads();
            if (act && t < 64) {
                psum_c[(size_t)(gt >> 5) * L + l0 + t] = sls[t] + sls[64 + t];
                psq_c [(size_t)(gt >> 5) * L + l0 + t] = slq[t] + slq[64 + t];
            }
        }
        grid_barrier(gcnt, ggen);
    }

    // ---------------- final LN apply (layer-3 stats in buffer B) -----------
    {
        const int team = tid >> 8;
        const int t = tid & 255;
        if (team < 2) {
            const int gt = bid * 2 + team;       // 0..511
            const int tx = t & 63;
            const int ty = t >> 6;
            const int l = (gt & 31) * 64 + tx;
            const int s = gt >> 5;

            float S = 0.f, Q = 0.f;
            #pragma unroll
            for (int k = 0; k < NSTRIPE; ++k) {
                S += psumB[(size_t)k * L + l];
                Q += psqB[(size_t)k * L + l];
            }
            const float invH = 1.0f / (float)H;
            float mu = S * invH;
            float rstd = rsqrtf(Q * invH - mu * mu + LN_EPS);

            const int hbase = s * 32;
            #pragma unroll
            for (int j = 0; j < 8; ++j) {
                int h = hbase + ty + j * 4;
                if (h < H) {
                    float v = out[(size_t)h * L + l];
                    out[(size_t)h * L + l] = (v - mu) * rstd * ln_g[h] + ln_b[h];
                }
            }
        }
    }
}

// ---------------------------------------------------------------------------
extern "C" void kernel_launch(void* const* d_in, const int* in_sizes, int n_in,
                              void* d_out, int out_size, void* d_ws, size_t ws_size,
                              hipStream_t stream) {
    const float* Z          = (const float*)d_in[0];
    const float* log_dt     = (const float*)d_in[1];
    const float* A_real_log = (const float*)d_in[2];
    const float* A_imag     = (const float*)d_in[3];
    const float* C_re       = (const float*)d_in[4];
    const float* C_im       = (const float*)d_in[5];
    const float* D_skip     = (const float*)d_in[6];
    const float* glu_w      = (const float*)d_in[7];
    const float* glu_b      = (const float*)d_in[8];
    const float* ln_g       = (const float*)d_in[9];
    const float* ln_b       = (const float*)d_in[10];

    float* out = (float*)d_out;
    float* ws  = (float*)d_ws;

    unsigned* gcnt = (unsigned*)ws;               // barrier state (memset 0)
    unsigned* ggen = gcnt + 1;
    float* base  = ws + 64;                       // 256 B reserved
    float* wr    = base;
    float* wi    = wr + HN;
    float* cr    = wi + HN;
    float* ci    = cr + HN;
    float* psumA = ci + HN;                       // (NSTRIPE,L) each
    float* psqA  = psumA + (size_t)NSTRIPE * L;
    float* psumB = psqA + (size_t)NSTRIPE * L;
    float* psqB  = psumB + (size_t)NSTRIPE * L;
    ushort* yb  = (ushort*)(psqB + (size_t)NSTRIPE * L);  // (H,L) bf16
    ushort* wbf = yb + (size_t)H * L;                     // (2H,HP) bf16

    hipMemsetAsync(d_ws, 0, 256, stream);

    s4_mega<<<NBLK, 1024, 0, stream>>>(
        Z, log_dt, A_real_log, A_imag, C_re, C_im, D_skip,
        glu_w, glu_b, ln_g, ln_b, out,
        wr, wi, cr, ci, psumA, psqA, psumB, psqB,
        yb, wbf, gcnt, ggen);
}

// Round 13
// 232.218 us; speedup vs baseline: 2.5080x; 2.5080x over previous
//
#include <hip/hip_runtime.h>
#include <hip/hip_bf16.h>
#include <math.h>

#define H 511
#define L 2048
#define NST 32
#define NLAYERS 4
#define LN_EPS 1e-5f
#define NCH 32             // chunks per channel (conv)
#define TC (L / NCH)       // 64 steps per chunk
#define HN (H * NST)       // 16352
#define HP 512             // K padded
#define GBK 64
#define GBN 64
#define NSTRIPE 16         // LN h-stripes of 32

typedef __attribute__((ext_vector_type(8))) short short8;
typedef __attribute__((ext_vector_type(4))) float f32x4;

__device__ __forceinline__ ushort f2bf(float v) {
    __hip_bfloat16 b = __float2bfloat16(v);
    return *reinterpret_cast<ushort*>(&b);
}

// ---------------------------------------------------------------------------
// Merged precompute: per-(h,n) coefs + w^64 (idx < HN) + W->bf16 (idx < 2H*HP).
// ---------------------------------------------------------------------------
__global__ __launch_bounds__(256) void pre_kernel(
    const float* __restrict__ log_dt,
    const float* __restrict__ A_real_log,
    const float* __restrict__ A_imag,
    const float* __restrict__ C_re,
    const float* __restrict__ C_im,
    const float* __restrict__ W,
    float* __restrict__ wr_o, float* __restrict__ wi_o,
    float* __restrict__ cr_o, float* __restrict__ ci_o,
    float* __restrict__ w64r_o, float* __restrict__ w64i_o,
    ushort* __restrict__ wbf)
{
    int idx = blockIdx.x * blockDim.x + threadIdx.x;
    if (idx < HN) {
        int h = idx / NST;
        float Ar = -expf(A_real_log[idx]);
        float Ai = A_imag[idx];
        float dt = expf(log_dt[h]);
        float dr = Ar * dt, di = Ai * dt;
        float er = expf(dr);
        float wr = er * cosf(di);
        float wi = er * sinf(di);
        float den = Ar * Ar + Ai * Ai;
        float a = wr - 1.0f, b = wi;
        float inv = 1.0f / den;
        float qr = (a * Ar + b * Ai) * inv;
        float qi = (b * Ar - a * Ai) * inv;
        wr_o[idx] = wr; wi_o[idx] = wi;
        cr_o[idx] = 2.0f * (C_re[idx] * qr - C_im[idx] * qi);
        ci_o[idx] = 2.0f * (C_re[idx] * qi + C_im[idx] * qr);
        // w^64 by 6 squarings
        float sr = wr, si = wi;
        #pragma unroll
        for (int k = 0; k < 6; ++k) {
            float nr = sr * sr - si * si;
            float ni = 2.0f * sr * si;
            sr = nr; si = ni;
        }
        w64r_o[idx] = sr; w64i_o[idx] = si;
    }
    if (idx < 2 * H * HP) {
        int r = idx / HP, k = idx % HP;
        float v = (k < H) ? W[(size_t)r * H + k] : 0.0f;
        wbf[idx] = f2bf(v);
    }
}

// ---------------------------------------------------------------------------
// DPP helpers: sum across each 32-lane half; result lands in lanes 31 and 63.
// ---------------------------------------------------------------------------
template <int CTRL, int ROW_MASK>
__device__ __forceinline__ float dpp_add(float x) {
    int r = __builtin_amdgcn_update_dpp(0, __float_as_int(x), CTRL, ROW_MASK, 0xf, true);
    return x + __int_as_float(r);
}
__device__ __forceinline__ float reduce32_to_lane31(float p) {
    p = dpp_add<0x111, 0xf>(p);  // row_shr:1
    p = dpp_add<0x112, 0xf>(p);  // row_shr:2
    p = dpp_add<0x114, 0xf>(p);  // row_shr:4
    p = dpp_add<0x118, 0xf>(p);  // row_shr:8
    p = dpp_add<0x142, 0xa>(p);  // row_bcast:15 into rows 1,3
    return p;                    // lane31 = sum(0..31), lane63 = sum(32..63)
}

__device__ __forceinline__ float gelu_tanh(float v) {
    const float c0 = 0.7978845608028654f;  // sqrt(2/pi)
    float t = tanhf(c0 * (v + 0.044715f * v * v * v));
    return 0.5f * v * (1.0f + t);
}

// ---------------------------------------------------------------------------
// Fused conv: one block = ONE channel, 1024 thr = 32 chunks of 64 steps.
// Phase2 is a Kogge-Stone scan across chunks (all threads active, shuffles).
// launch_bounds(1024,8): VGPR<=64 -> 2 blocks/CU co-resident (latency hiding).
// ---------------------------------------------------------------------------
__global__ __launch_bounds__(1024, 8) void conv_fused(
    const float* __restrict__ z,       // (H,L) fp32
    const float* __restrict__ wr_,
    const float* __restrict__ wi_,
    const float* __restrict__ cr_,
    const float* __restrict__ ci_,
    const float* __restrict__ w64r_,
    const float* __restrict__ w64i_,
    const float* __restrict__ D_skip,
    ushort* __restrict__ yb)           // (H,L) bf16
{
    __shared__ float zs[L];            // 8 KB
    __shared__ float ber[NCH][NST];    // 4 KB
    __shared__ float bei[NCH][NST];    // 4 KB
    __shared__ float ysf[L];           // 8 KB

    const int tid  = threadIdx.x;
    const int wv   = tid >> 6;          // wave 0..15
    const int half = (tid >> 5) & 1;
    const int ln   = tid & 31;          // state index n
    const int c    = wv * 2 + half;     // chunk 0..31
    const int h    = blockIdx.x;

    *(float2*)&zs[tid * 2] = *(const float2*)&z[(size_t)h * L + tid * 2];

    const int cidx = h * NST + ln;
    const float wr = wr_[cidx], wi = wi_[cidx];
    const float cr = cr_[cidx], ci = ci_[cidx];
    const float Dh = D_skip[h];
    __syncthreads();

    // phase 1: local scan of chunk c (carry 0)
    float sr = 0.f, si = 0.f;
    {
        const float* zp = &zs[c * TC];
        #pragma unroll 8
        for (int l = 0; l < TC; ++l) {
            float zl = zp[l];
            float nsr = fmaf(wr, sr, fmaf(-wi, si, zl));
            float nsi = fmaf(wr, si, wi * sr);
            sr = nsr; si = nsi;
        }
    }
    ber[c][ln] = sr;
    bei[c][ln] = si;
    __syncthreads();

    // phase 2: Kogge-Stone scan across the 32 chunks, all threads active.
    // Thread (n2, c2): I_c = S_c + w64 * I_{c-1}; step d adds W^d * I[c-d].
    {
        const int lam = tid & 63;
        const int c2 = lam & 31;
        const int n2 = ((tid >> 6) << 1) | (lam >> 5);
        float Ir = ber[c2][n2], Ii = bei[c2][n2];
        float Wr = w64r_[h * NST + n2], Wi = w64i_[h * NST + n2];
        #pragma unroll
        for (int d = 1; d < 32; d <<= 1) {
            float pr = __shfl_up(Ir, d, 32);
            float pi = __shfl_up(Ii, d, 32);
            if (c2 < d) { pr = 0.f; pi = 0.f; }
            float tr = fmaf(Wr, pr, -Wi * pi);
            float ti = fmaf(Wr, pi,  Wi * pr);
            Ir += tr; Ii += ti;
            float nWr = Wr * Wr - Wi * Wi;
            float nWi = 2.0f * Wr * Wi;
            Wr = nWr; Wi = nWi;
        }
        // carry into chunk c2 = inclusive I at c2-1
        float Cr = __shfl_up(Ir, 1, 32);
        float Ci = __shfl_up(Ii, 1, 32);
        if (c2 == 0) { Cr = 0.f; Ci = 0.f; }
        __syncthreads();   // all reads of ber/bei done before overwrite
        ber[c2][n2] = Cr;
        bei[c2][n2] = Ci;
    }
    __syncthreads();

    // phase 3: rescan with carry + C-dot + reduce + D-skip (preactivation)
    sr = ber[c][ln];
    si = bei[c][ln];
    {
        const float* zp = &zs[c * TC];
        float* yp = &ysf[c * TC];
        #pragma unroll 4
        for (int l = 0; l < TC; ++l) {
            float zl = zp[l];
            float nsr = fmaf(wr, sr, fmaf(-wi, si, zl));
            float nsi = fmaf(wr, si, wi * sr);
            sr = nsr; si = nsi;
            float p = fmaf(cr, sr, -ci * si);
            p = reduce32_to_lane31(p);
            if (ln == 31) yp[l] = fmaf(Dh, zl, p);
        }
    }
    __syncthreads();

    // epilogue: all lanes, gelu + bf16, coalesced ushort2 stores
    {
        ushort2 v;
        v.x = f2bf(gelu_tanh(ysf[tid * 2]));
        v.y = f2bf(gelu_tanh(ysf[tid * 2 + 1]));
        *(ushort2*)&yb[(size_t)h * L + tid * 2] = v;
    }
}

// ---------------------------------------------------------------------------
// MFMA GLU GEMM + fused LN-stats (round-10 proven, unchanged).
// ---------------------------------------------------------------------------
__global__ __launch_bounds__(256) void glu_mfma(
    const ushort* __restrict__ wbf,   // (2H, HP) bf16
    const ushort* __restrict__ yb,    // (H, L) bf16
    const float* __restrict__ bias,   // (2H)
    const float* __restrict__ zres,   // (H,L)
    float* __restrict__ out,          // (H,L)
    float* __restrict__ psum,         // (NSTRIPE,L)
    float* __restrict__ psq)          // (NSTRIPE,L)
{
    __shared__ ushort As1[32 * GBK];       // 4 KB
    __shared__ ushort As2[32 * GBK];       // 4 KB
    __shared__ ushort Bs[GBN * GBK];       // 8 KB
    __shared__ ushort tempT[4][32 * 40];   // 10 KB
    __shared__ float  sls[2][64];
    __shared__ float  slq[2][64];

    const int tid = threadIdx.x;
    const int h0 = blockIdx.y * 32;
    const int l0 = blockIdx.x * GBN;
    const int wid = tid >> 6;
    const int lane = tid & 63;
    const int wrow = (wid >> 1) * 16;
    const int wcol = (wid & 1) * 32;

    f32x4 acc1[2] = {{0.f,0.f,0.f,0.f},{0.f,0.f,0.f,0.f}};
    f32x4 acc2[2] = {{0.f,0.f,0.f,0.f},{0.f,0.f,0.f,0.f}};

    const int ar = tid >> 3;
    const int ak = tid & 7;
    const int hq1 = (h0 + ar < H) ? (h0 + ar) : (H - 1);
    const int hq2 = hq1 + H;
    const int aswz = ak ^ (ar & 7);

    const int tm   = tid >> 6;
    const int t64  = tid & 63;
    const int ksub = (tm & 1) * 32;
    const int lsub = (tm >> 1) * 32;
    const int bkl  = t64 >> 1;
    const int bhalf= t64 & 1;
    const int blr  = t64 >> 1;
    const int bkh  = t64 & 1;

    for (int k0 = 0; k0 < HP; k0 += GBK) {
        {
            short8 va1 = *(const short8*)&wbf[(size_t)hq1 * HP + k0 + ak * 8];
            short8 va2 = *(const short8*)&wbf[(size_t)hq2 * HP + k0 + ak * 8];
            *(short8*)&As1[ar * GBK + aswz * 8] = va1;
            *(short8*)&As2[ar * GBK + aswz * 8] = va2;
        }
        {
            const int kg = k0 + ksub + bkl;
            short8 v0 = {0,0,0,0,0,0,0,0}, v1 = {0,0,0,0,0,0,0,0};
            if (kg < H) {
                const ushort* row = &yb[(size_t)kg * L + l0 + lsub + bhalf * 16];
                v0 = *(const short8*)&row[0];
                v1 = *(const short8*)&row[8];
            }
            ushort* tp = &tempT[tm][0];
            #pragma unroll
            for (int j = 0; j < 8; ++j)
                tp[(bhalf * 16 + j) * 40 + bkl] = (ushort)v0[j];
            #pragma unroll
            for (int j = 0; j < 8; ++j)
                tp[(bhalf * 16 + 8 + j) * 40 + bkl] = (ushort)v1[j];
        }
        __syncthreads();
        {
            const ushort* tp = &tempT[tm][0];
            short8 b0 = *(const short8*)&tp[blr * 40 + bkh * 16];
            short8 b1 = *(const short8*)&tp[blr * 40 + bkh * 16 + 8];
            const int L_ = lsub + blr;
            const int kg0 = (ksub >> 3) + bkh * 2;
            *(short8*)&Bs[L_ * GBK + ((kg0    ) ^ (L_ & 7)) * 8] = b0;
            *(short8*)&Bs[L_ * GBK + ((kg0 + 1) ^ (L_ & 7)) * 8] = b1;
        }
        __syncthreads();

        #pragma unroll
        for (int kk = 0; kk < 2; ++kk) {
            const int arow = wrow + (lane & 15);
            const int kg = kk * 4 + (lane >> 4);
            short8 a1 = *(const short8*)&As1[arow * GBK + (kg ^ (arow & 7)) * 8];
            short8 a2 = *(const short8*)&As2[arow * GBK + (kg ^ (arow & 7)) * 8];
            #pragma unroll
            for (int nf = 0; nf < 2; ++nf) {
                const int brow = wcol + nf * 16 + (lane & 15);
                short8 b = *(const short8*)&Bs[brow * GBK + (kg ^ (brow & 7)) * 8];
                acc1[nf] = __builtin_amdgcn_mfma_f32_16x16x32_bf16(a1, b, acc1[nf], 0, 0, 0);
                acc2[nf] = __builtin_amdgcn_mfma_f32_16x16x32_bf16(a2, b, acc2[nf], 0, 0, 0);
            }
        }
        __syncthreads();
    }

    // ---- epilogue: GLU + residual -> out, plus LN partial stats ----
    float ps[2] = {0.f, 0.f}, pq[2] = {0.f, 0.f};
    #pragma unroll
    for (int nf = 0; nf < 2; ++nf) {
        const int col = l0 + wcol + nf * 16 + (lane & 15);
        #pragma unroll
        for (int r = 0; r < 4; ++r) {
            const int h = h0 + wrow + (lane >> 4) * 4 + r;
            if (h < H) {
                float v1 = acc1[nf][r] + bias[h];
                float v2 = acc2[nf][r] + bias[h + H];
                float o = v1 * (1.0f / (1.0f + expf(-v2))) + zres[(size_t)h * L + col];
                out[(size_t)h * L + col] = o;
                ps[nf] += o;
                pq[nf] = fmaf(o, o, pq[nf]);
            }
        }
    }
    #pragma unroll
    for (int nf = 0; nf < 2; ++nf) {
        ps[nf] += __shfl_xor(ps[nf], 16, 64);
        ps[nf] += __shfl_xor(ps[nf], 32, 64);
        pq[nf] += __shfl_xor(pq[nf], 16, 64);
        pq[nf] += __shfl_xor(pq[nf], 32, 64);
        if ((lane >> 4) == 0) {
            int cl = wcol + nf * 16 + lane;
            sls[wid >> 1][cl] = ps[nf];
            slq[wid >> 1][cl] = pq[nf];
        }
    }
    __syncthreads();
    if (tid < 64) {
        psum[(size_t)blockIdx.y * L + l0 + tid] = sls[0][tid] + sls[1][tid];
        psq [(size_t)blockIdx.y * L + l0 + tid] = slq[0][tid] + slq[1][tid];
    }
}

// ---------------------------------------------------------------------------
// LN phase 2 (round-10 proven): fold partials -> mu/rstd; apply stripe.
// ---------------------------------------------------------------------------
__global__ __launch_bounds__(256) void ln_apply(
    const float* __restrict__ zpre,
    const float* __restrict__ psum, const float* __restrict__ psq,
    const float* __restrict__ g, const float* __restrict__ b,
    float* __restrict__ out)
{
    const int tx = threadIdx.x & 63;
    const int ty = threadIdx.x >> 6;
    const int l = blockIdx.x * 64 + tx;
    const int s = blockIdx.y;

    float S = 0.f, Q = 0.f;
    #pragma unroll
    for (int k = 0; k < NSTRIPE; ++k) {
        S += psum[(size_t)k * L + l];
        Q += psq[(size_t)k * L + l];
    }
    const float invH = 1.0f / (float)H;
    float mu = S * invH;
    float var = Q * invH - mu * mu;
    float rstd = rsqrtf(var + LN_EPS);

    const int hbase = s * 32;
    #pragma unroll
    for (int j = 0; j < 8; ++j) {
        int h = hbase + ty + j * 4;
        if (h < H) {
            float v = zpre[(size_t)h * L + l];
            out[(size_t)h * L + l] = (v - mu) * rstd * g[h] + b[h];
        }
    }
}

// ---------------------------------------------------------------------------
extern "C" void kernel_launch(void* const* d_in, const int* in_sizes, int n_in,
                              void* d_out, int out_size, void* d_ws, size_t ws_size,
                              hipStream_t stream) {
    const float* Z          = (const float*)d_in[0];
    const float* log_dt     = (const float*)d_in[1];
    const float* A_real_log = (const float*)d_in[2];
    const float* A_imag     = (const float*)d_in[3];
    const float* C_re       = (const float*)d_in[4];
    const float* C_im       = (const float*)d_in[5];
    const float* D_skip     = (const float*)d_in[6];
    const float* glu_w      = (const float*)d_in[7];
    const float* glu_b      = (const float*)d_in[8];
    const float* ln_g       = (const float*)d_in[9];
    const float* ln_b       = (const float*)d_in[10];

    float* out = (float*)d_out;
    float* ws  = (float*)d_ws;

    float* wr    = ws;
    float* wi    = wr + HN;
    float* cr    = wi + HN;
    float* ci    = cr + HN;
    float* w64r  = ci + HN;
    float* w64i  = w64r + HN;
    float* zbuf  = w64i + HN;                      // (H,L) fp32
    float* psum  = zbuf + (size_t)H * L;           // (NSTRIPE,L)
    float* psq   = psum + (size_t)NSTRIPE * L;
    ushort* yb  = (ushort*)(psq + (size_t)NSTRIPE * L);   // (H,L) bf16
    ushort* wbf = yb + (size_t)H * L;                     // (2H,HP) bf16

    pre_kernel<<<(2 * H * HP + 255) / 256, 256, 0, stream>>>(
        log_dt, A_real_log, A_imag, C_re, C_im, glu_w,
        wr, wi, cr, ci, w64r, w64i, wbf);

    const dim3 gg(L / GBN, (H + 31) / 32);
    const dim3 lg(L / 64, NSTRIPE);

    for (int layer = 0; layer < NLAYERS; ++layer) {
        const float* zcur = (layer == 0) ? Z : zbuf;

        conv_fused<<<H, 1024, 0, stream>>>(
            zcur, wr, wi, cr, ci, w64r, w64i, D_skip, yb);
        glu_mfma<<<gg, 256, 0, stream>>>(wbf, yb, glu_b, zcur, out, psum, psq);

        float* lnout = (layer < NLAYERS - 1) ? zbuf : out;
        ln_apply<<<lg, 256, 0, stream>>>(out, psum, psq, ln_g, ln_b, lnout);
    }
}